// Round 9
// baseline (14995.236 us; speedup 1.0000x reference)
//
#include <hip/hip_runtime.h>
#include <hip/hip_bf16.h>

typedef __hip_bfloat16 bf16;
typedef __attribute__((ext_vector_type(8))) short short8;
typedef __attribute__((ext_vector_type(4))) float f32x4;

#define NN 20000
#define NE 80000
#define DD 128
#define NITER 15
#define HSTRIDE 136   // 272 B row stride: 16B-aligned rows, 2-way LDS aliasing (free)
#define GRID 625      // = NE/128 edge tiles; <= 768 co-resident (50KiB LDS -> 3 blk/CU)

__device__ inline void gload16(const void* g, void* l) {
  __builtin_amdgcn_global_load_lds(
      (const __attribute__((address_space(1))) void*)g,
      (__attribute__((address_space(3))) void*)l, 16, 0, 0);
}

__device__ inline float bfbits2f(unsigned int hi16) {
  union { unsigned int u; float f; } c; c.u = hi16; return c.f;
}

__device__ inline float readin(const void* p, int i, int fl) {
  return fl ? (float)((const bf16*)p)[i] : ((const float*)p)[i];
}

// Device-scope grid barrier: all GRID blocks co-resident (persistent kernel).
// release fence -> agent-scope arrive -> spin on generation -> acquire fence.
__device__ inline void gbar(int* cnt, int* gen, int nb) {
  __syncthreads();
  if (threadIdx.x == 0) {
    __threadfence();   // release: my global writes visible device-wide
    int g = __hip_atomic_load(gen, __ATOMIC_RELAXED, __HIP_MEMORY_SCOPE_AGENT);
    int a = __hip_atomic_fetch_add(cnt, 1, __ATOMIC_ACQ_REL, __HIP_MEMORY_SCOPE_AGENT);
    if (a == nb - 1) {
      __hip_atomic_store(cnt, 0, __ATOMIC_RELAXED, __HIP_MEMORY_SCOPE_AGENT);
      __hip_atomic_fetch_add(gen, 1, __ATOMIC_ACQ_REL, __HIP_MEMORY_SCOPE_AGENT);
    } else {
      while (__hip_atomic_load(gen, __ATOMIC_ACQUIRE, __HIP_MEMORY_SCOPE_AGENT) == g)
        __builtin_amdgcn_s_sleep(2);
    }
    __threadfence();   // acquire: others' writes visible to me
  }
  __syncthreads();
}

// ---------------------------------------------------------------------------
// One fused 3-layer-MLP tile (128 rows x 128 cols), round-8 structure:
// 4 row-split waves, B via double-buffered global_load_lds, A direct-to-reg,
// LDS-free LayerNorm, bf16 residual state read-modify-write (own rows only).
// AMODE 1: A0 = concat(xb[row[m]], xb[col[m]], eb[m])  (K0=384)
// AMODE 2: A0 = concat(xb[m], aggb[m])                 (K0=256)
// ---------------------------------------------------------------------------
template<int K0, int AMODE>
__device__ void mlp_tile(int m0,
    const bf16* S0b, const bf16* S1b, const int* eidx,
    const bf16* W0t, const bf16* W1t, const bf16* W2t,
    const float* b0, const float* b1, const float* b2,
    const float* gamma, const float* beta,
    bf16* st, int M, bf16* Bls, bf16* Hls)
{
  const int tid  = threadIdx.x;
  const int lane = tid & 63;
  const int wv   = tid >> 6;
  const int l15  = lane & 15, quad = lane >> 4;
  const int scol = tid >> 2;
  const int sk8  = (tid & 3) * 8;

  int rowm[2], ir[2], ic[2];
#pragma unroll
  for (int mi = 0; mi < 2; mi++) {
    rowm[mi] = min(m0 + wv * 32 + mi * 16 + l15, M - 1);
    if (AMODE == 1) { ir[mi] = eidx[rowm[mi]]; ic[mi] = eidx[NE + rowm[mi]]; }
  }

  auto dmaW = [&](const bf16* W, int K, int kk, int buf) {
    gload16(W + (size_t)scol * K + kk + sk8,        Bls + buf * 4096 + scol * 32 + sk8);
    gload16(W + (size_t)(scol + 64) * K + kk + sk8, Bls + buf * 4096 + (scol + 64) * 32 + sk8);
  };
  auto gatherA = [&](int kk, short8 a[2]) {
    const int ks = (kk & 127) + quad * 8;
#pragma unroll
    for (int mi = 0; mi < 2; mi++) {
      const bf16* base;
      if (AMODE == 1) {
        const int seg = kk >> 7;
        base = (seg == 0) ? S0b + (size_t)ir[mi] * DD
             : (seg == 1) ? S0b + (size_t)ic[mi] * DD
                          : S1b + (size_t)rowm[mi] * DD;
      } else {
        base = (kk >> 7) ? S1b + (size_t)rowm[mi] * DD
                         : S0b + (size_t)rowm[mi] * DD;
      }
      a[mi] = *(const short8*)(base + ks);
    }
  };

  f32x4 acc[2][8];
  auto zacc = [&]() {
#pragma unroll
    for (int i = 0; i < 2; i++)
#pragma unroll
      for (int j = 0; j < 8; j++) acc[i][j] = (f32x4){0.f, 0.f, 0.f, 0.f};
  };
  auto slabMfmaA = [&](const short8 a[2], int buf) {
    short8 bfr[8];
#pragma unroll
    for (int ni = 0; ni < 8; ni++)
      bfr[ni] = *(const short8*)(Bls + buf * 4096 + (ni * 16 + l15) * 32 + quad * 8);
#pragma unroll
    for (int mi = 0; mi < 2; mi++)
#pragma unroll
      for (int ni = 0; ni < 8; ni++)
        acc[mi][ni] = __builtin_amdgcn_mfma_f32_16x16x32_bf16(a[mi], bfr[ni], acc[mi][ni], 0, 0, 0);
  };
  auto slabMfmaH = [&](int kk, int buf) {
    short8 a[2], bfr[8];
#pragma unroll
    for (int mi = 0; mi < 2; mi++)
      a[mi] = *(const short8*)(Hls + (wv * 32 + mi * 16 + l15) * HSTRIDE + kk + quad * 8);
#pragma unroll
    for (int ni = 0; ni < 8; ni++)
      bfr[ni] = *(const short8*)(Bls + buf * 4096 + (ni * 16 + l15) * 32 + quad * 8);
#pragma unroll
    for (int mi = 0; mi < 2; mi++)
#pragma unroll
      for (int ni = 0; ni < 8; ni++)
        acc[mi][ni] = __builtin_amdgcn_mfma_f32_16x16x32_bf16(a[mi], bfr[ni], acc[mi][ni], 0, 0, 0);
  };
  auto writeH = [&](const float* bias) {
    float bv[8];
#pragma unroll
    for (int ni = 0; ni < 8; ni++) bv[ni] = bias[ni * 16 + l15];
#pragma unroll
    for (int mi = 0; mi < 2; mi++)
#pragma unroll
      for (int r = 0; r < 4; r++) {
        const int row = wv * 32 + mi * 16 + quad * 4 + r;
#pragma unroll
        for (int ni = 0; ni < 8; ni++)
          Hls[row * HSTRIDE + ni * 16 + l15] = (bf16)fmaxf(acc[mi][ni][r] + bv[ni], 0.f);
      }
  };

  constexpr int NS1 = K0 / 32;   // 12 or 8 (even)

  // Phase 1
  zacc();
  short8 aCur[2], aNxt[2];
  dmaW(W0t, K0, 0, 0);
  gatherA(0, aCur);
  __syncthreads();
#pragma unroll
  for (int s = 0; s < NS1; s++) {
    if (s + 1 < NS1) {
      dmaW(W0t, K0, (s + 1) * 32, (s + 1) & 1);
      gatherA((s + 1) * 32, aNxt);
    } else {
      dmaW(W1t, 128, 0, NS1 & 1);
    }
    slabMfmaA(aCur, s & 1);
    __syncthreads();
#pragma unroll
    for (int mi = 0; mi < 2; mi++) aCur[mi] = aNxt[mi];
  }
  writeH(b0);
  __syncthreads();

  // Phase 2
  zacc();
#pragma unroll
  for (int s = 0; s < 4; s++) {
    if (s < 3) dmaW(W1t, 128, (s + 1) * 32, (NS1 + s + 1) & 1);
    else       dmaW(W2t, 128, 0,            (NS1 + 4) & 1);
    slabMfmaH(s * 32, (NS1 + s) & 1);
    __syncthreads();
  }
  writeH(b1);
  __syncthreads();

  // Phase 3 + LN + residual
  zacc();
#pragma unroll
  for (int s = 0; s < 4; s++) {
    if (s < 3) dmaW(W2t, 128, (s + 1) * 32, (NS1 + 4 + s + 1) & 1);
    slabMfmaH(s * 32, (NS1 + 4 + s) & 1);
    if (s < 3) __syncthreads();
  }

  float bv[8], gv[8], btv[8];
#pragma unroll
  for (int ni = 0; ni < 8; ni++) {
    const int col = ni * 16 + l15;
    bv[ni] = b2[col]; gv[ni] = gamma[col]; btv[ni] = beta[col];
  }
#pragma unroll
  for (int mi = 0; mi < 2; mi++)
#pragma unroll
    for (int r = 0; r < 4; r++) {
      float a = 0.f, bq = 0.f;
#pragma unroll
      for (int ni = 0; ni < 8; ni++) {
        const float v = acc[mi][ni][r] + bv[ni];
        a += v; bq += v * v;
      }
#pragma unroll
      for (int off = 1; off < 16; off <<= 1) {
        a  += __shfl_xor(a, off);
        bq += __shfl_xor(bq, off);
      }
      const float mu = a * (1.0f / 128.0f);
      const float var = fmaxf(bq * (1.0f / 128.0f) - mu * mu, 0.0f);
      const float rs = rsqrtf(var + 1e-5f);
      const int m = m0 + wv * 32 + mi * 16 + quad * 4 + r;
      if (m < M) {
#pragma unroll
        for (int ni = 0; ni < 8; ni++) {
          const int col = ni * 16 + l15;
          const float v = acc[mi][ni][r] + bv[ni];
          const float lnv = (v - mu) * rs * gv[ni] + btv[ni];
          const size_t idx = (size_t)m * DD + col;
          st[idx] = (bf16)(lnv + (float)st[idx]);
        }
      }
    }
}

// ---------------------------------------------------------------------------
struct MegaP {
  const void *x_in, *e_in;
  const void *eW0, *eW1, *eW2, *nW0, *nW1, *nW2;
  const void *eB0, *eB1, *eB2, *eG, *eBt, *nB0, *nB1, *nB2, *nG, *nBt;
  const int* eidx;
  bf16 *xb, *eb, *aggb;
  bf16 *eW0t, *eW1t, *eW2t, *nW0t, *nW1t, *nW2t;
  float *eB0f, *eB1f, *eB2f, *eGf, *eBtf, *nB0f, *nB1f, *nB2f, *nGf, *nBtf;
  const int *offs, *sorted;
  int *flag, *cnt, *gen;
  void* out;
};

__global__ __launch_bounds__(256, 3) void mega(MegaP P) {
  __shared__ __align__(16) bf16 Bls[2 * 128 * 32];
  __shared__ __align__(16) bf16 Hls[128 * HSTRIDE];

  const int tid = threadIdx.x;
  const int bid = blockIdx.x;
  const int G   = gridDim.x;
  const int gtid = bid * 256 + tid;
  const int gstride = G * 256;

  // ---- phase 0a: dtype detect (block 0; LDS scratch overlaid on Hls) ----
  if (bid == 0) {
    int* cs = (int*)Hls; int* ct = cs + 256;
    int sane = 0, tot = 0;
    for (int i = 2 * tid; i < 16384; i += 512) {
      unsigned short v = ((const unsigned short*)P.x_in)[i];
      int e = (v >> 7) & 0xFF; tot++;
      if (v == 0 || (e >= 80 && e <= 170)) sane++;
    }
    cs[tid] = sane; ct[tid] = tot;
    __syncthreads();
    for (int o = 128; o > 0; o >>= 1) {
      if (tid < o) { cs[tid] += cs[tid + o]; ct[tid] += ct[tid + o]; }
      __syncthreads();
    }
    if (tid == 0) *P.flag = (cs[0] * 10 > ct[0] * 7) ? 1 : 0;
  }
  gbar(P.cnt, P.gen, G);
  const int fl = *(volatile int*)P.flag;

  // ---- phase 0b: conversions (grid-stride) ----
  for (int i = gtid; i < NN * DD; i += gstride) P.xb[i] = (bf16)readin(P.x_in, i, fl);
  for (int i = gtid; i < NE * DD; i += gstride) P.eb[i] = (bf16)readin(P.e_in, i, fl);
  auto w2t = [&](const void* W, bf16* Wt, int K) {
    const int tot = NITER * K * DD;
    for (int i = gtid; i < tot; i += gstride) {
      float v = readin(W, i, fl);
      int it = i / (K * DD);
      int rem = i - it * K * DD;
      int k = rem >> 7, n = rem & 127;
      Wt[(size_t)it * K * DD + (size_t)n * K + k] = (bf16)v;
    }
  };
  w2t(P.eW0, P.eW0t, 384); w2t(P.eW1, P.eW1t, 128); w2t(P.eW2, P.eW2t, 128);
  w2t(P.nW0, P.nW0t, 256); w2t(P.nW1, P.nW1t, 128); w2t(P.nW2, P.nW2t, 128);
  auto bcv = [&](const void* B, float* Bf) {
    for (int i = gtid; i < NITER * DD; i += gstride) Bf[i] = readin(B, i, fl);
  };
  bcv(P.eB0, P.eB0f); bcv(P.eB1, P.eB1f); bcv(P.eB2, P.eB2f);
  bcv(P.eG, P.eGf);   bcv(P.eBt, P.eBtf);
  bcv(P.nB0, P.nB0f); bcv(P.nB1, P.nB1f); bcv(P.nB2, P.nB2f);
  bcv(P.nG, P.nGf);   bcv(P.nBt, P.nBtf);
  gbar(P.cnt, P.gen, G);

  // ---- 15 message-passing iterations ----
  const int ET = NE / 128;              // 625
  const int NT = (NN + 127) / 128;      // 157
  const int lane = tid & 63;
  const int wv4  = tid >> 6;

  for (int t = 0; t < NITER; t++) {
    for (int tile = bid; tile < ET; tile += G)
      mlp_tile<384, 1>(tile * 128, P.xb, P.eb, P.eidx,
          P.eW0t + (size_t)t * 384 * DD, P.eW1t + (size_t)t * 128 * DD,
          P.eW2t + (size_t)t * 128 * DD,
          P.eB0f + t * DD, P.eB1f + t * DD, P.eB2f + t * DD,
          P.eGf + t * DD, P.eBtf + t * DD, P.eb, NE, Bls, Hls);
    gbar(P.cnt, P.gen, G);

    for (int node = bid * 4 + wv4; node < NN; node += G * 4) {
      const int s = P.offs[node], e2 = P.offs[node + 1];
      float a0 = 0.f, a1 = 0.f;
      for (int i = s; i < e2; i++) {
        const int e = P.sorted[i];
        unsigned int v = *(const unsigned int*)(P.eb + (size_t)e * DD + 2 * lane);
        a0 += bfbits2f(v << 16);
        a1 += bfbits2f(v & 0xFFFF0000u);
      }
      bf16 o0 = (bf16)a0, o1 = (bf16)a1;
      unsigned int pack = (unsigned int)(*(unsigned short*)&o0)
                        | ((unsigned int)(*(unsigned short*)&o1) << 16);
      *(unsigned int*)(P.aggb + (size_t)node * DD + 2 * lane) = pack;
    }
    gbar(P.cnt, P.gen, G);

    for (int tile = bid; tile < NT; tile += G)
      mlp_tile<256, 2>(tile * 128, P.xb, P.aggb, nullptr,
          P.nW0t + (size_t)t * 256 * DD, P.nW1t + (size_t)t * 128 * DD,
          P.nW2t + (size_t)t * 128 * DD,
          P.nB0f + t * DD, P.nB1f + t * DD, P.nB2f + t * DD,
          P.nGf + t * DD, P.nBtf + t * DD, P.xb, NN, Bls, Hls);
    gbar(P.cnt, P.gen, G);
  }

  // ---- output ----
  const int total = (NN + NE) * DD;
  for (int i = gtid; i < total; i += gstride) {
    bf16 v = (i < NN * DD) ? P.xb[i] : P.eb[i - NN * DD];
    if (fl) ((bf16*)P.out)[i] = v;
    else    ((float*)P.out)[i] = (float)v;
  }
}

// --------------------------- CSR build (pre-kernels) -----------------------
__global__ void zero_kernel(int* __restrict__ p, int n) {
  int i = blockIdx.x * 256 + threadIdx.x;
  if (i < n) p[i] = 0;
}

__global__ void hist_kernel(const int* __restrict__ eidx, int* __restrict__ counts) {
  int e = blockIdx.x * 256 + threadIdx.x;
  if (e < NE) atomicAdd(&counts[eidx[NE + e]], 1);
}

__global__ void scan_kernel(const int* __restrict__ counts, int* __restrict__ offs,
                            int* __restrict__ cursor) {
  __shared__ int sums[1024];
  const int t = threadIdx.x;
  const int base = t * 20;
  int local[20];
  int s = 0;
  for (int i = 0; i < 20; i++) {
    int idx = base + i;
    int c = (idx < NN) ? counts[idx] : 0;
    local[i] = s; s += c;
  }
  sums[t] = s;
  __syncthreads();
  for (int off = 1; off < 1024; off <<= 1) {
    int v = 0;
    if (t >= off) v = sums[t - off];
    __syncthreads();
    if (t >= off) sums[t] += v;
    __syncthreads();
  }
  int excl = (t == 0) ? 0 : sums[t - 1];
  for (int i = 0; i < 20; i++) {
    int idx = base + i;
    if (idx < NN) { offs[idx] = excl + local[i]; cursor[idx] = 0; }
  }
  if (t == 1023) offs[NN] = sums[1023];
}

__global__ void fill_kernel(const int* __restrict__ eidx, const int* __restrict__ offs,
                            int* __restrict__ cursor, int* __restrict__ sorted) {
  int e = blockIdx.x * 256 + threadIdx.x;
  if (e < NE) {
    int n = eidx[NE + e];
    int p = atomicAdd(&cursor[n], 1);
    sorted[offs[n] + p] = e;
  }
}

// ---------------------------------------------------------------------------
extern "C" void kernel_launch(void* const* d_in, const int* in_sizes, int n_in,
                              void* d_out, int out_size, void* d_ws, size_t ws_size,
                              hipStream_t stream) {
  char* ws = (char*)d_ws;
  size_t off = 0;
  auto alloc = [&](size_t bytes) -> char* {
    char* p = ws + off;
    off = (off + bytes + 255) & ~(size_t)255;
    return p;
  };

  MegaP P;
  P.x_in = d_in[0];  P.e_in = d_in[1];
  P.eW0 = d_in[2];   P.eB0 = d_in[3];
  P.eW1 = d_in[4];   P.eB1 = d_in[5];
  P.eW2 = d_in[6];   P.eB2 = d_in[7];
  P.eG  = d_in[8];   P.eBt = d_in[9];
  P.nW0 = d_in[10];  P.nB0 = d_in[11];
  P.nW1 = d_in[12];  P.nB1 = d_in[13];
  P.nW2 = d_in[14];  P.nB2 = d_in[15];
  P.nG  = d_in[16];  P.nBt = d_in[17];
  P.eidx = (const int*)d_in[18];

  P.xb   = (bf16*)alloc((size_t)NN * DD * 2);
  P.eb   = (bf16*)alloc((size_t)NE * DD * 2);
  P.aggb = (bf16*)alloc((size_t)NN * DD * 2);
  P.eW0t = (bf16*)alloc((size_t)NITER * 384 * DD * 2);
  P.eW1t = (bf16*)alloc((size_t)NITER * 128 * DD * 2);
  P.eW2t = (bf16*)alloc((size_t)NITER * 128 * DD * 2);
  P.nW0t = (bf16*)alloc((size_t)NITER * 256 * DD * 2);
  P.nW1t = (bf16*)alloc((size_t)NITER * 128 * DD * 2);
  P.nW2t = (bf16*)alloc((size_t)NITER * 128 * DD * 2);
  const int NB = NITER * DD;
  P.eB0f = (float*)alloc(NB * 4);
  P.eB1f = (float*)alloc(NB * 4);
  P.eB2f = (float*)alloc(NB * 4);
  P.eGf  = (float*)alloc(NB * 4);
  P.eBtf = (float*)alloc(NB * 4);
  P.nB0f = (float*)alloc(NB * 4);
  P.nB1f = (float*)alloc(NB * 4);
  P.nB2f = (float*)alloc(NB * 4);
  P.nGf  = (float*)alloc(NB * 4);
  P.nBtf = (float*)alloc(NB * 4);
  int* counts = (int*)alloc((size_t)NN * 4);
  int* cursor = (int*)alloc((size_t)NN * 4);
  int* offs   = (int*)alloc((size_t)(NN + 1) * 4);
  int* sorted = (int*)alloc((size_t)NE * 4);
  int* misc   = (int*)alloc(16);        // [0]=flag [1]=cnt [2]=gen
  P.offs = offs; P.sorted = sorted;
  P.flag = misc; P.cnt = misc + 1; P.gen = misc + 2;
  P.out = d_out;

  // CSR build + barrier/flag zeroing (ws is poisoned 0xAA by the harness)
  zero_kernel<<<(NN + 255) / 256, 256, 0, stream>>>(counts, NN);
  zero_kernel<<<1, 64, 0, stream>>>(misc, 4);
  hist_kernel<<<(NE + 255) / 256, 256, 0, stream>>>(P.eidx, counts);
  scan_kernel<<<1, 1024, 0, stream>>>(counts, offs, cursor);
  fill_kernel<<<(NE + 255) / 256, 256, 0, stream>>>(P.eidx, offs, cursor, sorted);

  // Persistent mega-kernel: all phases, grid-barrier separated.
  mega<<<GRID, 256, 0, stream>>>(P);
}

// Round 10
// 1509.094 us; speedup vs baseline: 9.9366x; 9.9366x over previous
//
#include <hip/hip_runtime.h>
#include <hip/hip_bf16.h>

typedef __hip_bfloat16 bf16;
typedef __attribute__((ext_vector_type(8))) short short8;
typedef __attribute__((ext_vector_type(4))) float f32x4;

#define NN 20000
#define NE 80000
#define DD 128
#define NITER 15
#define HSTRIDE 136   // 272 B row stride: 16B-aligned rows, 2-way LDS aliasing (free)

__device__ inline void gload16(const void* g, void* l) {
  __builtin_amdgcn_global_load_lds(
      (const __attribute__((address_space(1))) void*)g,
      (__attribute__((address_space(3))) void*)l, 16, 0, 0);
}

__device__ inline float bfbits2f(unsigned int hi16) {
  union { unsigned int u; float f; } c; c.u = hi16; return c.f;
}

__device__ inline float readin(const void* p, int i, int fl) {
  return fl ? (float)((const bf16*)p)[i] : ((const float*)p)[i];
}

// ---------------------------------------------------------------------------
// detzero: blocks 0..78 zero counts; block 79 runs dtype detection.
// flag = 1 -> bf16 inputs ; flag = 0 -> fp32 inputs.
// ---------------------------------------------------------------------------
__global__ void detzero_kernel(const unsigned short* __restrict__ x,
                               int* __restrict__ counts, int* __restrict__ flag) {
  const int bid = blockIdx.x, t = threadIdx.x;
  if (bid < 79) {
    int i = bid * 256 + t;
    if (i < NN) counts[i] = 0;
    return;
  }
  __shared__ int cs[256], ct[256];
  int sane = 0, tot = 0;
  for (int i = 2 * t; i < 16384; i += 512) {
    unsigned short v = x[i];
    int e = (v >> 7) & 0xFF;
    tot++;
    if (v == 0 || (e >= 80 && e <= 170)) sane++;
  }
  cs[t] = sane; ct[t] = tot;
  __syncthreads();
  for (int o = 128; o > 0; o >>= 1) {
    if (t < o) { cs[t] += cs[t + o]; ct[t] += ct[t + o]; }
    __syncthreads();
  }
  if (t == 0) *flag = (cs[0] * 10 > ct[0] * 7) ? 1 : 0;
}

// ---------------------------------------------------------------------------
// convert_all: one grid-stride kernel for every input canonicalization:
// x->xb, e->eb, 6 weight transposes ([K][128] -> [128][K] bf16), 10 biases->fp32.
// ---------------------------------------------------------------------------
#define CX  (NN * DD)
#define CE  (NE * DD)
#define CW0 (NITER * 384 * DD)
#define CW1 (NITER * 128 * DD)
#define CNW0 (NITER * 256 * DD)
#define CB  (NITER * DD)
#define BX0 CX
#define BX1 (BX0 + CE)
#define BX7 (BX1 + CW0 + CW1 + CW1 + CNW0 + CW1 + CW1)
#define BX8 (BX7 + 10 * CB)

struct CvtP {
  const void *x, *e;
  const void* w[6];
  bf16 *xb, *eb;
  bf16* wt[6];
  const void* bs[10];
  float* bd[10];
  const int* flag;
};

__global__ void convert_all(CvtP P) {
  const int fl = *P.flag;
  const int gstride = gridDim.x * 256;
  for (int i = blockIdx.x * 256 + threadIdx.x; i < BX8; i += gstride) {
    if (i < BX0) {
      P.xb[i] = (bf16)readin(P.x, i, fl);
    } else if (i < BX1) {
      P.eb[i - BX0] = (bf16)readin(P.e, i - BX0, fl);
    } else if (i < BX7) {
      int j = i - BX1, w;
      if (j < CW0) { w = 0; }
      else if ((j -= CW0) < CW1) { w = 1; }
      else if ((j -= CW1) < CW1) { w = 2; }
      else if ((j -= CW1) < CNW0) { w = 3; }
      else if ((j -= CNW0) < CW1) { w = 4; }
      else { j -= CW1; w = 5; }
      const int K = (w == 0) ? 384 : (w == 3) ? 256 : 128;
      float v = readin(P.w[w], j, fl);
      int it = j / (K * DD);
      int rem = j - it * K * DD;
      int k = rem >> 7, n = rem & 127;
      P.wt[w][(size_t)it * K * DD + (size_t)n * K + k] = (bf16)v;
    } else {
      int j = i - BX7;
      int b = j / CB, r = j - b * CB;
      P.bd[b][r] = readin(P.bs[b], r, fl);
    }
  }
}

// ---------------------------------------------------------------------------
// Edge MLP (round-8 proven): 128x128 tile, 4 row-split waves, B via
// double-buffered global_load_lds, A direct-to-register (gather), LDS-free
// LayerNorm, bf16 residual state RMW (own rows only).
// A0 = concat(xb[row[m]], xb[col[m]], eb[m])  (K0=384)
// ---------------------------------------------------------------------------
__global__ __launch_bounds__(256, 3) void edge_mlp(
    const bf16* __restrict__ xb,
    const bf16* eb,                  // aliases st
    const int*  __restrict__ eidx,
    const bf16* __restrict__ W0t, const bf16* __restrict__ W1t,
    const bf16* __restrict__ W2t,
    const float* __restrict__ b0, const float* __restrict__ b1,
    const float* __restrict__ b2,
    const float* __restrict__ gamma, const float* __restrict__ beta,
    bf16* st, int M)
{
  constexpr int K0 = 384, NS1 = 12;
  __shared__ __align__(16) bf16 Bls[2][128 * 32];
  __shared__ __align__(16) bf16 Hls[128 * HSTRIDE];

  const int tid  = threadIdx.x;
  const int lane = tid & 63;
  const int wv   = tid >> 6;
  const int l15  = lane & 15, quad = lane >> 4;
  const int m0   = blockIdx.x * 128;
  const int scol = tid >> 2;
  const int sk8  = (tid & 3) * 8;

  int rowm[2], ir[2], ic[2];
#pragma unroll
  for (int mi = 0; mi < 2; mi++) {
    rowm[mi] = min(m0 + wv * 32 + mi * 16 + l15, M - 1);
    ir[mi] = eidx[rowm[mi]]; ic[mi] = eidx[NE + rowm[mi]];
  }

  auto dmaW = [&](const bf16* W, int K, int kk, int buf) {
    gload16(W + (size_t)scol * K + kk + sk8,        &Bls[buf][scol * 32 + sk8]);
    gload16(W + (size_t)(scol + 64) * K + kk + sk8, &Bls[buf][(scol + 64) * 32 + sk8]);
  };
  auto gatherA = [&](int kk, short8 a[2]) {
    const int ks = (kk & 127) + quad * 8;
#pragma unroll
    for (int mi = 0; mi < 2; mi++) {
      const int seg = kk >> 7;
      const bf16* base = (seg == 0) ? xb + (size_t)ir[mi] * DD
                       : (seg == 1) ? xb + (size_t)ic[mi] * DD
                                    : eb + (size_t)rowm[mi] * DD;
      a[mi] = *(const short8*)(base + ks);
    }
  };

  f32x4 acc[2][8];
  auto zacc = [&]() {
#pragma unroll
    for (int i = 0; i < 2; i++)
#pragma unroll
      for (int j = 0; j < 8; j++) acc[i][j] = (f32x4){0.f, 0.f, 0.f, 0.f};
  };
  auto slabMfmaA = [&](const short8 a[2], int buf) {
    short8 bfr[8];
#pragma unroll
    for (int ni = 0; ni < 8; ni++)
      bfr[ni] = *(const short8*)&Bls[buf][(ni * 16 + l15) * 32 + quad * 8];
#pragma unroll
    for (int mi = 0; mi < 2; mi++)
#pragma unroll
      for (int ni = 0; ni < 8; ni++)
        acc[mi][ni] = __builtin_amdgcn_mfma_f32_16x16x32_bf16(a[mi], bfr[ni], acc[mi][ni], 0, 0, 0);
  };
  auto slabMfmaH = [&](int kk, int buf) {
    short8 a[2], bfr[8];
#pragma unroll
    for (int mi = 0; mi < 2; mi++)
      a[mi] = *(const short8*)&Hls[(wv * 32 + mi * 16 + l15) * HSTRIDE + kk + quad * 8];
#pragma unroll
    for (int ni = 0; ni < 8; ni++)
      bfr[ni] = *(const short8*)&Bls[buf][(ni * 16 + l15) * 32 + quad * 8];
#pragma unroll
    for (int mi = 0; mi < 2; mi++)
#pragma unroll
      for (int ni = 0; ni < 8; ni++)
        acc[mi][ni] = __builtin_amdgcn_mfma_f32_16x16x32_bf16(a[mi], bfr[ni], acc[mi][ni], 0, 0, 0);
  };
  auto writeH = [&](const float* bias) {
    float bv[8];
#pragma unroll
    for (int ni = 0; ni < 8; ni++) bv[ni] = bias[ni * 16 + l15];
#pragma unroll
    for (int mi = 0; mi < 2; mi++)
#pragma unroll
      for (int r = 0; r < 4; r++) {
        const int row = wv * 32 + mi * 16 + quad * 4 + r;
#pragma unroll
        for (int ni = 0; ni < 8; ni++)
          Hls[row * HSTRIDE + ni * 16 + l15] = (bf16)fmaxf(acc[mi][ni][r] + bv[ni], 0.f);
      }
  };

  // Phase 1
  zacc();
  short8 aCur[2], aNxt[2];
  dmaW(W0t, K0, 0, 0);
  gatherA(0, aCur);
  __syncthreads();
#pragma unroll
  for (int s = 0; s < NS1; s++) {
    if (s + 1 < NS1) {
      dmaW(W0t, K0, (s + 1) * 32, (s + 1) & 1);
      gatherA((s + 1) * 32, aNxt);
    } else {
      dmaW(W1t, 128, 0, NS1 & 1);
    }
    slabMfmaA(aCur, s & 1);
    __syncthreads();
    aCur[0] = aNxt[0]; aCur[1] = aNxt[1];
  }
  writeH(b0);
  __syncthreads();

  // Phase 2
  zacc();
#pragma unroll
  for (int s = 0; s < 4; s++) {
    if (s < 3) dmaW(W1t, 128, (s + 1) * 32, (NS1 + s + 1) & 1);
    else       dmaW(W2t, 128, 0,            (NS1 + 4) & 1);
    slabMfmaH(s * 32, (NS1 + s) & 1);
    __syncthreads();
  }
  writeH(b1);
  __syncthreads();

  // Phase 3 + LN + residual
  zacc();
#pragma unroll
  for (int s = 0; s < 4; s++) {
    if (s < 3) dmaW(W2t, 128, (s + 1) * 32, (NS1 + 4 + s + 1) & 1);
    slabMfmaH(s * 32, (NS1 + 4 + s) & 1);
    if (s < 3) __syncthreads();
  }

  float bv[8], gv[8], btv[8];
#pragma unroll
  for (int ni = 0; ni < 8; ni++) {
    const int col = ni * 16 + l15;
    bv[ni] = b2[col]; gv[ni] = gamma[col]; btv[ni] = beta[col];
  }
#pragma unroll
  for (int mi = 0; mi < 2; mi++)
#pragma unroll
    for (int r = 0; r < 4; r++) {
      float a = 0.f, bq = 0.f;
#pragma unroll
      for (int ni = 0; ni < 8; ni++) {
        const float v = acc[mi][ni][r] + bv[ni];
        a += v; bq += v * v;
      }
#pragma unroll
      for (int off = 1; off < 16; off <<= 1) {
        a  += __shfl_xor(a, off);
        bq += __shfl_xor(bq, off);
      }
      const float mu = a * (1.0f / 128.0f);
      const float var = fmaxf(bq * (1.0f / 128.0f) - mu * mu, 0.0f);
      const float rs = rsqrtf(var + 1e-5f);
      const int m = m0 + wv * 32 + mi * 16 + quad * 4 + r;
      if (m < M) {
#pragma unroll
        for (int ni = 0; ni < 8; ni++) {
          const int col = ni * 16 + l15;
          const float v = acc[mi][ni][r] + bv[ni];
          const float lnv = (v - mu) * rs * gv[ni] + btv[ni];
          const size_t idx = (size_t)m * DD + col;
          st[idx] = (bf16)(lnv + (float)st[idx]);
        }
      }
    }
}

// ---------------------------------------------------------------------------
// Node MLP with INTEGRATED aggregation. 64x128 tile, 4 waves (16 rows each,
// MI=1). Step 0: each wave CSR-sums its own 16 nodes' incoming edges into
// the Hls region (bf16, packed-uint writes; conflict-free). Phase-1 seg-1
// gather reads agg from LDS (each wave reads only rows it wrote -> intra-wave
// visibility, no extra barrier). writeH overwrites Hls only after all agg
// reads. A0 = concat(xb[m], aggLDS[m])  (K0=256).
// ---------------------------------------------------------------------------
__global__ __launch_bounds__(256, 4) void node_mlp(
    const bf16* xb,                  // aliases st
    const bf16* __restrict__ eb,
    const int*  __restrict__ offs,
    const int*  __restrict__ sorted,
    const bf16* __restrict__ W0t, const bf16* __restrict__ W1t,
    const bf16* __restrict__ W2t,
    const float* __restrict__ b0, const float* __restrict__ b1,
    const float* __restrict__ b2,
    const float* __restrict__ gamma, const float* __restrict__ beta,
    bf16* st, int M)
{
  constexpr int K0 = 256, NS1 = 8;
  __shared__ __align__(16) bf16 Bls[2][128 * 32];
  __shared__ __align__(16) bf16 Hls[64 * HSTRIDE];

  const int tid  = threadIdx.x;
  const int lane = tid & 63;
  const int wv   = tid >> 6;
  const int l15  = lane & 15, quad = lane >> 4;
  const int m0   = blockIdx.x * 64;
  const int scol = tid >> 2;
  const int sk8  = (tid & 3) * 8;

  // ---- step 0: aggregate own 16 nodes into Hls (agg overlay) ----
  for (int j = 0; j < 16; j++) {
    const int n = m0 + wv * 16 + j;
    if (n < M) {
      const int s = offs[n], e2 = offs[n + 1];
      float a0 = 0.f, a1 = 0.f;
      for (int i = s; i < e2; i++) {
        const int e = sorted[i];
        unsigned int v = *(const unsigned int*)(eb + (size_t)e * DD + 2 * lane);
        a0 += bfbits2f(v << 16);
        a1 += bfbits2f(v & 0xFFFF0000u);
      }
      bf16 o0 = (bf16)a0, o1 = (bf16)a1;
      unsigned int pack = (unsigned int)(*(unsigned short*)&o0)
                        | ((unsigned int)(*(unsigned short*)&o1) << 16);
      *(unsigned int*)&Hls[(wv * 16 + j) * HSTRIDE + 2 * lane] = pack;
    }
  }

  const int rowm = min(m0 + wv * 16 + l15, M - 1);

  auto dmaW = [&](const bf16* W, int K, int kk, int buf) {
    gload16(W + (size_t)scol * K + kk + sk8,        &Bls[buf][scol * 32 + sk8]);
    gload16(W + (size_t)(scol + 64) * K + kk + sk8, &Bls[buf][(scol + 64) * 32 + sk8]);
  };
  auto gatherA = [&](int kk, short8* a) {
    const int ks = (kk & 127) + quad * 8;
    if (kk < 128) *a = *(const short8*)(xb + (size_t)rowm * DD + ks);
    else          *a = *(const short8*)&Hls[(rowm - m0) * HSTRIDE + ks];
  };

  f32x4 acc[8];
  auto zacc = [&]() {
#pragma unroll
    for (int j = 0; j < 8; j++) acc[j] = (f32x4){0.f, 0.f, 0.f, 0.f};
  };
  auto slabMfmaA = [&](short8 a, int buf) {
    short8 bfr[8];
#pragma unroll
    for (int ni = 0; ni < 8; ni++)
      bfr[ni] = *(const short8*)&Bls[buf][(ni * 16 + l15) * 32 + quad * 8];
#pragma unroll
    for (int ni = 0; ni < 8; ni++)
      acc[ni] = __builtin_amdgcn_mfma_f32_16x16x32_bf16(a, bfr[ni], acc[ni], 0, 0, 0);
  };
  auto slabMfmaH = [&](int kk, int buf) {
    short8 a = *(const short8*)&Hls[(wv * 16 + l15) * HSTRIDE + kk + quad * 8];
    short8 bfr[8];
#pragma unroll
    for (int ni = 0; ni < 8; ni++)
      bfr[ni] = *(const short8*)&Bls[buf][(ni * 16 + l15) * 32 + quad * 8];
#pragma unroll
    for (int ni = 0; ni < 8; ni++)
      acc[ni] = __builtin_amdgcn_mfma_f32_16x16x32_bf16(a, bfr[ni], acc[ni], 0, 0, 0);
  };
  auto writeH = [&](const float* bias) {
    float bv[8];
#pragma unroll
    for (int ni = 0; ni < 8; ni++) bv[ni] = bias[ni * 16 + l15];
#pragma unroll
    for (int r = 0; r < 4; r++) {
      const int row = wv * 16 + quad * 4 + r;
#pragma unroll
      for (int ni = 0; ni < 8; ni++)
        Hls[row * HSTRIDE + ni * 16 + l15] = (bf16)fmaxf(acc[ni][r] + bv[ni], 0.f);
    }
  };

  // Phase 1 (agg consumed from LDS during slabs 4..7; writeH after)
  zacc();
  short8 aCur, aNxt;
  dmaW(W0t, K0, 0, 0);
  gatherA(0, &aCur);
  __syncthreads();
#pragma unroll
  for (int s = 0; s < NS1; s++) {
    if (s + 1 < NS1) {
      dmaW(W0t, K0, (s + 1) * 32, (s + 1) & 1);
      gatherA((s + 1) * 32, &aNxt);
    } else {
      dmaW(W1t, 128, 0, NS1 & 1);
    }
    slabMfmaA(aCur, s & 1);
    __syncthreads();
    aCur = aNxt;
  }
  writeH(b0);
  __syncthreads();

  // Phase 2
  zacc();
#pragma unroll
  for (int s = 0; s < 4; s++) {
    if (s < 3) dmaW(W1t, 128, (s + 1) * 32, (NS1 + s + 1) & 1);
    else       dmaW(W2t, 128, 0,            (NS1 + 4) & 1);
    slabMfmaH(s * 32, (NS1 + s) & 1);
    __syncthreads();
  }
  writeH(b1);
  __syncthreads();

  // Phase 3 + LN + residual
  zacc();
#pragma unroll
  for (int s = 0; s < 4; s++) {
    if (s < 3) dmaW(W2t, 128, (s + 1) * 32, (NS1 + 4 + s + 1) & 1);
    slabMfmaH(s * 32, (NS1 + 4 + s) & 1);
    if (s < 3) __syncthreads();
  }

  float bv[8], gv[8], btv[8];
#pragma unroll
  for (int ni = 0; ni < 8; ni++) {
    const int col = ni * 16 + l15;
    bv[ni] = b2[col]; gv[ni] = gamma[col]; btv[ni] = beta[col];
  }
#pragma unroll
  for (int r = 0; r < 4; r++) {
    float a = 0.f, bq = 0.f;
#pragma unroll
    for (int ni = 0; ni < 8; ni++) {
      const float v = acc[ni][r] + bv[ni];
      a += v; bq += v * v;
    }
#pragma unroll
    for (int off = 1; off < 16; off <<= 1) {
      a  += __shfl_xor(a, off);
      bq += __shfl_xor(bq, off);
    }
    const float mu = a * (1.0f / 128.0f);
    const float var = fmaxf(bq * (1.0f / 128.0f) - mu * mu, 0.0f);
    const float rs = rsqrtf(var + 1e-5f);
    const int m = m0 + wv * 16 + quad * 4 + r;
    if (m < M) {
#pragma unroll
      for (int ni = 0; ni < 8; ni++) {
        const int col = ni * 16 + l15;
        const float v = acc[ni][r] + bv[ni];
        const float lnv = (v - mu) * rs * gv[ni] + btv[ni];
        const size_t idx = (size_t)m * DD + col;
        st[idx] = (bf16)(lnv + (float)st[idx]);
      }
    }
  }
}

// --------------------------- CSR build ------------------------------------
__global__ void hist_kernel(const int* __restrict__ eidx, int* __restrict__ counts) {
  int e = blockIdx.x * 256 + threadIdx.x;
  if (e < NE) atomicAdd(&counts[eidx[NE + e]], 1);
}

__global__ void scan_kernel(const int* __restrict__ counts, int* __restrict__ offs,
                            int* __restrict__ cursor) {
  __shared__ int sums[1024];
  const int t = threadIdx.x;
  const int base = t * 20;
  int local[20];
  int s = 0;
  for (int i = 0; i < 20; i++) {
    int idx = base + i;
    int c = (idx < NN) ? counts[idx] : 0;
    local[i] = s; s += c;
  }
  sums[t] = s;
  __syncthreads();
  for (int off = 1; off < 1024; off <<= 1) {
    int v = 0;
    if (t >= off) v = sums[t - off];
    __syncthreads();
    if (t >= off) sums[t] += v;
    __syncthreads();
  }
  int excl = (t == 0) ? 0 : sums[t - 1];
  for (int i = 0; i < 20; i++) {
    int idx = base + i;
    if (idx < NN) { offs[idx] = excl + local[i]; cursor[idx] = 0; }
  }
  if (t == 1023) offs[NN] = sums[1023];
}

__global__ void fill_kernel(const int* __restrict__ eidx, const int* __restrict__ offs,
                            int* __restrict__ cursor, int* __restrict__ sorted) {
  int e = blockIdx.x * 256 + threadIdx.x;
  if (e < NE) {
    int n = eidx[NE + e];
    int p = atomicAdd(&cursor[n], 1);
    sorted[offs[n] + p] = e;
  }
}

// bf16 states -> d_out in detected dtype
__global__ void outwb_kernel(const bf16* __restrict__ xb, const bf16* __restrict__ eb,
                             void* __restrict__ out, const int* __restrict__ flag) {
  int i = blockIdx.x * 256 + threadIdx.x;
  const int nx = NN * DD, total = (NN + NE) * DD;
  if (i < total) {
    bf16 v = (i < nx) ? xb[i] : eb[i - nx];
    if (*flag) ((bf16*)out)[i] = v;
    else       ((float*)out)[i] = (float)v;
  }
}

// ---------------------------------------------------------------------------
extern "C" void kernel_launch(void* const* d_in, const int* in_sizes, int n_in,
                              void* d_out, int out_size, void* d_ws, size_t ws_size,
                              hipStream_t stream) {
  const int* eidx = (const int*)d_in[18];

  char* ws = (char*)d_ws;
  size_t off = 0;
  auto alloc = [&](size_t bytes) -> char* {
    char* p = ws + off;
    off = (off + bytes + 255) & ~(size_t)255;
    return p;
  };

  bf16* xb   = (bf16*)alloc((size_t)NN * DD * 2);
  bf16* eb   = (bf16*)alloc((size_t)NE * DD * 2);
  bf16* eW0t = (bf16*)alloc((size_t)CW0 * 2);
  bf16* eW1t = (bf16*)alloc((size_t)CW1 * 2);
  bf16* eW2t = (bf16*)alloc((size_t)CW1 * 2);
  bf16* nW0t = (bf16*)alloc((size_t)CNW0 * 2);
  bf16* nW1t = (bf16*)alloc((size_t)CW1 * 2);
  bf16* nW2t = (bf16*)alloc((size_t)CW1 * 2);
  float* bf_[10];
  for (int i = 0; i < 10; i++) bf_[i] = (float*)alloc(CB * 4);
  int* counts = (int*)alloc((size_t)NN * 4);
  int* cursor = (int*)alloc((size_t)NN * 4);
  int* offs   = (int*)alloc((size_t)(NN + 1) * 4);
  int* sorted = (int*)alloc((size_t)NE * 4);
  int* flag   = (int*)alloc(4);

  // 1) zero counts + detect dtype
  detzero_kernel<<<80, 256, 0, stream>>>((const unsigned short*)d_in[0], counts, flag);

  // 2) all conversions in one kernel
  CvtP C;
  C.x = d_in[0]; C.e = d_in[1];
  C.w[0] = d_in[2];  C.w[1] = d_in[4];  C.w[2] = d_in[6];
  C.w[3] = d_in[10]; C.w[4] = d_in[12]; C.w[5] = d_in[14];
  C.xb = xb; C.eb = eb;
  C.wt[0] = eW0t; C.wt[1] = eW1t; C.wt[2] = eW2t;
  C.wt[3] = nW0t; C.wt[4] = nW1t; C.wt[5] = nW2t;
  const int bsrc_idx[10] = {3, 5, 7, 8, 9, 11, 13, 15, 16, 17};
  for (int i = 0; i < 10; i++) { C.bs[i] = d_in[bsrc_idx[i]]; C.bd[i] = bf_[i]; }
  C.flag = flag;
  convert_all<<<2048, 256, 0, stream>>>(C);

  // 3) CSR
  hist_kernel<<<(NE + 255) / 256, 256, 0, stream>>>(eidx, counts);
  scan_kernel<<<1, 1024, 0, stream>>>(counts, offs, cursor);
  fill_kernel<<<(NE + 255) / 256, 256, 0, stream>>>(eidx, offs, cursor, sorted);

  const int egrid = NE / 128;               // 625
  const int ngrid = (NN + 63) / 64;         // 313

  // 4) message passing: 2 dispatches per iteration
  for (int t = 0; t < NITER; t++) {
    edge_mlp<<<egrid, 256, 0, stream>>>(
        xb, eb, eidx,
        eW0t + (size_t)t * 384 * DD, eW1t + (size_t)t * 128 * DD,
        eW2t + (size_t)t * 128 * DD,
        bf_[0] + t * DD, bf_[1] + t * DD, bf_[2] + t * DD,
        bf_[3] + t * DD, bf_[4] + t * DD, eb, NE);
    node_mlp<<<ngrid, 256, 0, stream>>>(
        xb, eb, offs, sorted,
        nW0t + (size_t)t * 256 * DD, nW1t + (size_t)t * 128 * DD,
        nW2t + (size_t)t * 128 * DD,
        bf_[5] + t * DD, bf_[6] + t * DD, bf_[7] + t * DD,
        bf_[8] + t * DD, bf_[9] + t * DD, xb, NN);
  }

  // 5) output
  outwb_kernel<<<((NN + NE) * DD + 255) / 256, 256, 0, stream>>>(xb, eb, d_out, flag);
}

// Round 11
// 1138.195 us; speedup vs baseline: 13.1746x; 1.3259x over previous
//
#include <hip/hip_runtime.h>
#include <hip/hip_bf16.h>

typedef __hip_bfloat16 bf16;
typedef __attribute__((ext_vector_type(8))) short short8;
typedef __attribute__((ext_vector_type(4))) float f32x4;

#define NN 20000
#define NE 80000
#define DD 128
#define NITER 15
#define HSTRIDE 136   // 272 B row stride: 16B-aligned rows, 2-way LDS aliasing (free)

__device__ inline void gload16(const void* g, void* l) {
  __builtin_amdgcn_global_load_lds(
      (const __attribute__((address_space(1))) void*)g,
      (__attribute__((address_space(3))) void*)l, 16, 0, 0);
}

__device__ inline float bfbits2f(unsigned int hi16) {
  union { unsigned int u; float f; } c; c.u = hi16; return c.f;
}

__device__ inline float readin(const void* p, int i, int fl) {
  return fl ? (float)((const bf16*)p)[i] : ((const float*)p)[i];
}

// ---------------------------------------------------------------------------
// detzero: blocks 0..78 zero counts; block 79 runs dtype detection.
// flag = 1 -> bf16 inputs ; flag = 0 -> fp32 inputs.
// ---------------------------------------------------------------------------
__global__ void detzero_kernel(const unsigned short* __restrict__ x,
                               int* __restrict__ counts, int* __restrict__ flag) {
  const int bid = blockIdx.x, t = threadIdx.x;
  if (bid < 79) {
    int i = bid * 256 + t;
    if (i < NN) counts[i] = 0;
    return;
  }
  __shared__ int cs[256], ct[256];
  int sane = 0, tot = 0;
  for (int i = 2 * t; i < 16384; i += 512) {
    unsigned short v = x[i];
    int e = (v >> 7) & 0xFF;
    tot++;
    if (v == 0 || (e >= 80 && e <= 170)) sane++;
  }
  cs[t] = sane; ct[t] = tot;
  __syncthreads();
  for (int o = 128; o > 0; o >>= 1) {
    if (t < o) { cs[t] += cs[t + o]; ct[t] += ct[t + o]; }
    __syncthreads();
  }
  if (t == 0) *flag = (cs[0] * 10 > ct[0] * 7) ? 1 : 0;
}

// ---------------------------------------------------------------------------
// convert_all: one grid-stride kernel for every input canonicalization.
// ---------------------------------------------------------------------------
#define CX  (NN * DD)
#define CE  (NE * DD)
#define CW0 (NITER * 384 * DD)
#define CW1 (NITER * 128 * DD)
#define CNW0 (NITER * 256 * DD)
#define CB  (NITER * DD)
#define BX0 CX
#define BX1 (BX0 + CE)
#define BX7 (BX1 + CW0 + CW1 + CW1 + CNW0 + CW1 + CW1)
#define BX8 (BX7 + 10 * CB)

struct CvtP {
  const void *x, *e;
  const void* w[6];
  bf16 *xb, *eb;
  bf16* wt[6];
  const void* bs[10];
  float* bd[10];
  const int* flag;
};

__global__ void convert_all(CvtP P) {
  const int fl = *P.flag;
  const int gstride = gridDim.x * 256;
  for (int i = blockIdx.x * 256 + threadIdx.x; i < BX8; i += gstride) {
    if (i < BX0) {
      P.xb[i] = (bf16)readin(P.x, i, fl);
    } else if (i < BX1) {
      P.eb[i - BX0] = (bf16)readin(P.e, i - BX0, fl);
    } else if (i < BX7) {
      int j = i - BX1, w;
      if (j < CW0) { w = 0; }
      else if ((j -= CW0) < CW1) { w = 1; }
      else if ((j -= CW1) < CW1) { w = 2; }
      else if ((j -= CW1) < CNW0) { w = 3; }
      else if ((j -= CNW0) < CW1) { w = 4; }
      else { j -= CW1; w = 5; }
      const int K = (w == 0) ? 384 : (w == 3) ? 256 : 128;
      float v = readin(P.w[w], j, fl);
      int it = j / (K * DD);
      int rem = j - it * K * DD;
      int k = rem >> 7, n = rem & 127;
      P.wt[w][(size_t)it * K * DD + (size_t)n * K + k] = (bf16)v;
    } else {
      int j = i - BX7;
      int b = j / CB, r = j - b * CB;
      P.bd[b][r] = readin(P.bs[b], r, fl);
    }
  }
}

// ---------------------------------------------------------------------------
// Fused 3-layer MLP, 64-row x 128-col tile, 4 waves (16 rows each, MI=1).
// B staged via double-buffered global_load_lds (one barrier per 32-K slab,
// DMA for slab s+1 in flight across slab s's compute); A direct-to-register.
// LDS-free LayerNorm (full row per wave); bf16 residual state RMW (own rows).
// LDS = 16K (B dbuf) + 17.4K (H) = 33.8 KB -> 4 blocks/CU (16 waves).
// AMODE 1: A0 = concat(xb[row[m]], xb[col[m]], eb[m])  (K0=384)
// AMODE 2: A0 = concat(xb[m], aggb[m])                 (K0=256)
// ---------------------------------------------------------------------------
template<int K0, int AMODE>
__global__ __launch_bounds__(256, 4) void fused_mlp(
    const bf16* S0b,                 // xb (may alias st for AMODE 2)
    const bf16* S1b,                 // eb (AMODE 1, aliases st) / aggb (AMODE 2)
    const int*  __restrict__ eidx,
    const bf16* __restrict__ W0t, const bf16* __restrict__ W1t,
    const bf16* __restrict__ W2t,
    const float* __restrict__ b0, const float* __restrict__ b1,
    const float* __restrict__ b2,
    const float* __restrict__ gamma, const float* __restrict__ beta,
    bf16* st, int M)
{
  constexpr int NS1 = K0 / 32;       // 12 or 8 (even)
  __shared__ __align__(16) bf16 Bls[2][128 * 32];
  __shared__ __align__(16) bf16 Hls[64 * HSTRIDE];

  const int tid  = threadIdx.x;
  const int lane = tid & 63;
  const int wv   = tid >> 6;
  const int l15  = lane & 15, quad = lane >> 4;
  const int m0   = blockIdx.x * 64;
  const int scol = tid >> 2;
  const int sk8  = (tid & 3) * 8;

  const int rowm = min(m0 + wv * 16 + l15, M - 1);
  int ir = 0, ic = 0;
  if (AMODE == 1) { ir = eidx[rowm]; ic = eidx[NE + rowm]; }

  auto dmaW = [&](const bf16* W, int K, int kk, int buf) {
    gload16(W + (size_t)scol * K + kk + sk8,        &Bls[buf][scol * 32 + sk8]);
    gload16(W + (size_t)(scol + 64) * K + kk + sk8, &Bls[buf][(scol + 64) * 32 + sk8]);
  };
  auto gatherA = [&](int kk, short8* a) {
    const int ks = (kk & 127) + quad * 8;
    const bf16* base;
    if (AMODE == 1) {
      const int seg = kk >> 7;
      base = (seg == 0) ? S0b + (size_t)ir * DD
           : (seg == 1) ? S0b + (size_t)ic * DD
                        : S1b + (size_t)rowm * DD;
    } else {
      base = (kk >> 7) ? S1b + (size_t)rowm * DD
                       : S0b + (size_t)rowm * DD;
    }
    *a = *(const short8*)(base + ks);
  };

  f32x4 acc[8];
  auto zacc = [&]() {
#pragma unroll
    for (int j = 0; j < 8; j++) acc[j] = (f32x4){0.f, 0.f, 0.f, 0.f};
  };
  auto slabMfmaA = [&](short8 a, int buf) {
    short8 bfr[8];
#pragma unroll
    for (int ni = 0; ni < 8; ni++)
      bfr[ni] = *(const short8*)&Bls[buf][(ni * 16 + l15) * 32 + quad * 8];
#pragma unroll
    for (int ni = 0; ni < 8; ni++)
      acc[ni] = __builtin_amdgcn_mfma_f32_16x16x32_bf16(a, bfr[ni], acc[ni], 0, 0, 0);
  };
  auto slabMfmaH = [&](int kk, int buf) {
    short8 a = *(const short8*)&Hls[(wv * 16 + l15) * HSTRIDE + kk + quad * 8];
    short8 bfr[8];
#pragma unroll
    for (int ni = 0; ni < 8; ni++)
      bfr[ni] = *(const short8*)&Bls[buf][(ni * 16 + l15) * 32 + quad * 8];
#pragma unroll
    for (int ni = 0; ni < 8; ni++)
      acc[ni] = __builtin_amdgcn_mfma_f32_16x16x32_bf16(a, bfr[ni], acc[ni], 0, 0, 0);
  };
  auto writeH = [&](const float* bias) {
    float bv[8];
#pragma unroll
    for (int ni = 0; ni < 8; ni++) bv[ni] = bias[ni * 16 + l15];
#pragma unroll
    for (int r = 0; r < 4; r++) {
      const int row = wv * 16 + quad * 4 + r;
#pragma unroll
      for (int ni = 0; ni < 8; ni++)
        Hls[row * HSTRIDE + ni * 16 + l15] = (bf16)fmaxf(acc[ni][r] + bv[ni], 0.f);
    }
  };

  // Phase 1
  zacc();
  short8 aCur, aNxt;
  dmaW(W0t, K0, 0, 0);
  gatherA(0, &aCur);
  __syncthreads();
#pragma unroll
  for (int s = 0; s < NS1; s++) {
    if (s + 1 < NS1) {
      dmaW(W0t, K0, (s + 1) * 32, (s + 1) & 1);
      gatherA((s + 1) * 32, &aNxt);
    } else {
      dmaW(W1t, 128, 0, NS1 & 1);
    }
    slabMfmaA(aCur, s & 1);
    __syncthreads();
    aCur = aNxt;
  }
  writeH(b0);
  __syncthreads();

  // Phase 2
  zacc();
#pragma unroll
  for (int s = 0; s < 4; s++) {
    if (s < 3) dmaW(W1t, 128, (s + 1) * 32, (NS1 + s + 1) & 1);
    else       dmaW(W2t, 128, 0,            (NS1 + 4) & 1);
    slabMfmaH(s * 32, (NS1 + s) & 1);
    __syncthreads();
  }
  writeH(b1);
  __syncthreads();

  // Phase 3 + LN + residual
  zacc();
#pragma unroll
  for (int s = 0; s < 4; s++) {
    if (s < 3) dmaW(W2t, 128, (s + 1) * 32, (NS1 + 4 + s + 1) & 1);
    slabMfmaH(s * 32, (NS1 + 4 + s) & 1);
    if (s < 3) __syncthreads();
  }

  float bv[8], gv[8], btv[8];
#pragma unroll
  for (int ni = 0; ni < 8; ni++) {
    const int col = ni * 16 + l15;
    bv[ni] = b2[col]; gv[ni] = gamma[col]; btv[ni] = beta[col];
  }
#pragma unroll
  for (int r = 0; r < 4; r++) {
    float a = 0.f, bq = 0.f;
#pragma unroll
    for (int ni = 0; ni < 8; ni++) {
      const float v = acc[ni][r] + bv[ni];
      a += v; bq += v * v;
    }
#pragma unroll
    for (int off = 1; off < 16; off <<= 1) {
      a  += __shfl_xor(a, off);
      bq += __shfl_xor(bq, off);
    }
    const float mu = a * (1.0f / 128.0f);
    const float var = fmaxf(bq * (1.0f / 128.0f) - mu * mu, 0.0f);
    const float rs = rsqrtf(var + 1e-5f);
    const int m = m0 + wv * 16 + quad * 4 + r;
    if (m < M) {
#pragma unroll
      for (int ni = 0; ni < 8; ni++) {
        const int col = ni * 16 + l15;
        const float v = acc[ni][r] + bv[ni];
        const float lnv = (v - mu) * rs * gv[ni] + btv[ni];
        const size_t idx = (size_t)m * DD + col;
        st[idx] = (bf16)(lnv + (float)st[idx]);
      }
    }
  }
}

// --------------------------- CSR build + aggregate -------------------------
__global__ void hist_kernel(const int* __restrict__ eidx, int* __restrict__ counts) {
  int e = blockIdx.x * 256 + threadIdx.x;
  if (e < NE) atomicAdd(&counts[eidx[NE + e]], 1);
}

__global__ void scan_kernel(const int* __restrict__ counts, int* __restrict__ offs,
                            int* __restrict__ cursor) {
  __shared__ int sums[1024];
  const int t = threadIdx.x;
  const int base = t * 20;
  int local[20];
  int s = 0;
  for (int i = 0; i < 20; i++) {
    int idx = base + i;
    int c = (idx < NN) ? counts[idx] : 0;
    local[i] = s; s += c;
  }
  sums[t] = s;
  __syncthreads();
  for (int off = 1; off < 1024; off <<= 1) {
    int v = 0;
    if (t >= off) v = sums[t - off];
    __syncthreads();
    if (t >= off) sums[t] += v;
    __syncthreads();
  }
  int excl = (t == 0) ? 0 : sums[t - 1];
  for (int i = 0; i < 20; i++) {
    int idx = base + i;
    if (idx < NN) { offs[idx] = excl + local[i]; cursor[idx] = 0; }
  }
  if (t == 1023) offs[NN] = sums[1023];
}

__global__ void fill_kernel(const int* __restrict__ eidx, const int* __restrict__ offs,
                            int* __restrict__ cursor, int* __restrict__ sorted) {
  int e = blockIdx.x * 256 + threadIdx.x;
  if (e < NE) {
    int n = eidx[NE + e];
    int p = atomicAdd(&cursor[n], 1);
    sorted[offs[n] + p] = e;
  }
}

// wave per node (fat grid: 20000 waves, 32 waves/CU -> latency well hidden):
// packed-uint bf16x2 loads, fp32 sums, bf16 out.
__global__ void aggregate_kernel(const bf16* __restrict__ eb, const int* __restrict__ offs,
                                 const int* __restrict__ sorted, bf16* __restrict__ aggb) {
  const int node = blockIdx.x * 4 + (threadIdx.x >> 6);
  const int lane = threadIdx.x & 63;
  if (node >= NN) return;
  const int s = offs[node], t = offs[node + 1];
  float a0 = 0.f, a1 = 0.f;
  for (int i = s; i < t; i++) {
    const int e = sorted[i];
    unsigned int v = *(const unsigned int*)(eb + (size_t)e * DD + 2 * lane);
    a0 += bfbits2f(v << 16);
    a1 += bfbits2f(v & 0xFFFF0000u);
  }
  bf16 o0 = (bf16)a0, o1 = (bf16)a1;
  unsigned int pack = (unsigned int)(*(unsigned short*)&o0)
                    | ((unsigned int)(*(unsigned short*)&o1) << 16);
  *(unsigned int*)(aggb + (size_t)node * DD + 2 * lane) = pack;
}

// bf16 states -> d_out in detected dtype
__global__ void outwb_kernel(const bf16* __restrict__ xb, const bf16* __restrict__ eb,
                             void* __restrict__ out, const int* __restrict__ flag) {
  int i = blockIdx.x * 256 + threadIdx.x;
  const int nx = NN * DD, total = (NN + NE) * DD;
  if (i < total) {
    bf16 v = (i < nx) ? xb[i] : eb[i - nx];
    if (*flag) ((bf16*)out)[i] = v;
    else       ((float*)out)[i] = (float)v;
  }
}

// ---------------------------------------------------------------------------
extern "C" void kernel_launch(void* const* d_in, const int* in_sizes, int n_in,
                              void* d_out, int out_size, void* d_ws, size_t ws_size,
                              hipStream_t stream) {
  const int* eidx = (const int*)d_in[18];

  char* ws = (char*)d_ws;
  size_t off = 0;
  auto alloc = [&](size_t bytes) -> char* {
    char* p = ws + off;
    off = (off + bytes + 255) & ~(size_t)255;
    return p;
  };

  bf16* xb   = (bf16*)alloc((size_t)NN * DD * 2);
  bf16* eb   = (bf16*)alloc((size_t)NE * DD * 2);
  bf16* aggb = (bf16*)alloc((size_t)NN * DD * 2);
  bf16* eW0t = (bf16*)alloc((size_t)CW0 * 2);
  bf16* eW1t = (bf16*)alloc((size_t)CW1 * 2);
  bf16* eW2t = (bf16*)alloc((size_t)CW1 * 2);
  bf16* nW0t = (bf16*)alloc((size_t)CNW0 * 2);
  bf16* nW1t = (bf16*)alloc((size_t)CW1 * 2);
  bf16* nW2t = (bf16*)alloc((size_t)CW1 * 2);
  float* bf_[10];
  for (int i = 0; i < 10; i++) bf_[i] = (float*)alloc(CB * 4);
  int* counts = (int*)alloc((size_t)NN * 4);
  int* cursor = (int*)alloc((size_t)NN * 4);
  int* offs   = (int*)alloc((size_t)(NN + 1) * 4);
  int* sorted = (int*)alloc((size_t)NE * 4);
  int* flag   = (int*)alloc(4);

  // 1) zero counts + detect dtype
  detzero_kernel<<<80, 256, 0, stream>>>((const unsigned short*)d_in[0], counts, flag);

  // 2) all conversions in one kernel
  CvtP C;
  C.x = d_in[0]; C.e = d_in[1];
  C.w[0] = d_in[2];  C.w[1] = d_in[4];  C.w[2] = d_in[6];
  C.w[3] = d_in[10]; C.w[4] = d_in[12]; C.w[5] = d_in[14];
  C.xb = xb; C.eb = eb;
  C.wt[0] = eW0t; C.wt[1] = eW1t; C.wt[2] = eW2t;
  C.wt[3] = nW0t; C.wt[4] = nW1t; C.wt[5] = nW2t;
  const int bsrc_idx[10] = {3, 5, 7, 8, 9, 11, 13, 15, 16, 17};
  for (int i = 0; i < 10; i++) { C.bs[i] = d_in[bsrc_idx[i]]; C.bd[i] = bf_[i]; }
  C.flag = flag;
  convert_all<<<2048, 256, 0, stream>>>(C);

  // 3) CSR
  hist_kernel<<<(NE + 255) / 256, 256, 0, stream>>>(eidx, counts);
  scan_kernel<<<1, 1024, 0, stream>>>(counts, offs, cursor);
  fill_kernel<<<(NE + 255) / 256, 256, 0, stream>>>(eidx, offs, cursor, sorted);

  const int egrid = NE / 64;                // 1250 (4 blocks/CU by LDS)
  const int ngrid = (NN + 63) / 64;         // 313

  // 4) message passing: 3 dispatches per iteration
  for (int t = 0; t < NITER; t++) {
    fused_mlp<384, 1><<<egrid, 256, 0, stream>>>(
        xb, eb, eidx,
        eW0t + (size_t)t * 384 * DD, eW1t + (size_t)t * 128 * DD,
        eW2t + (size_t)t * 128 * DD,
        bf_[0] + t * DD, bf_[1] + t * DD, bf_[2] + t * DD,
        bf_[3] + t * DD, bf_[4] + t * DD, eb, NE);
    aggregate_kernel<<<(NN + 3) / 4, 256, 0, stream>>>(eb, offs, sorted, aggb);
    fused_mlp<256, 2><<<ngrid, 256, 0, stream>>>(
        xb, aggb, nullptr,
        nW0t + (size_t)t * 256 * DD, nW1t + (size_t)t * 128 * DD,
        nW2t + (size_t)t * 128 * DD,
        bf_[5] + t * DD, bf_[6] + t * DD, bf_[7] + t * DD,
        bf_[8] + t * DD, bf_[9] + t * DD, xb, NN);
  }

  // 5) output
  outwb_kernel<<<((NN + NE) * DD + 255) / 256, 256, 0, stream>>>(xb, eb, d_out, flag);
}